// Round 7
// baseline (163.475 us; speedup 1.0000x reference)
//
#include <hip/hip_runtime.h>
#include <math.h>
#include <stdint.h>

#define N_NODES 100000
#define N_EDGES 1000000
#define N_NONLOOP (N_EDGES - N_NODES)          // 900000 edges needing accumulation
#define NXCD 8

// ---- binned-accumulation geometry ----
#define NP    16         // node partitions
#define PSZ   6250       // nodes per partition (100000/16)
#define PCAP  61440      // slot capacity per partition (mean 56.25K, +22 sigma)
#define GOWN  16         // owner blocks per partition -> 256 blocks
#define PROW  6272       // padded partial-row stride (floats, 64B-aligned)
#define NCHUNK 391       // ceil(PSZ/GOWN) nodes finalized per owner block

// Q20 fixed-point (fallback path only)
#define ACC_SCALE   1048576.0f
#define ACC_INV     (1.0f / 1048576.0f)

typedef float  vfloat4 __attribute__((ext_vector_type(4)));
typedef int    vint4   __attribute__((ext_vector_type(4)));
typedef unsigned long long u64;

// HW_REG_XCC_ID = 20 on gfx940+; read bits [3:0]
#define XCC_ID_HWREG (20 | ((4 - 1) << 11))
__device__ __forceinline__ int get_xcc() {
    return __builtin_amdgcn_s_getreg(XCC_ID_HWREG) & (NXCD - 1);
}
__device__ __forceinline__ void l2_atomic_add_u32(uint32_t* p, uint32_t v) {
    asm volatile("global_atomic_add %0, %1, off" :: "v"(p), "v"(v) : "memory");
}
__device__ __forceinline__ void l2_atomic_add_f32(float* p, float v) {
    asm volatile("global_atomic_add_f32 %0, %1, off" :: "v"(p), "v"(v) : "memory");
}

__device__ __forceinline__ float get_invtau(const int* __restrict__ training_step) {
    int step = training_step[0];
    float tau;
    if (step == -1) {
        tau = 0.1f;  // TEMP_EVAL
    } else {
        float frac = fminf((float)step / 10000.0f, 1.0f);
        tau = 1.0f + (0.1f - 1.0f) * frac;
    }
    return 1.0f / tau;
}

__device__ __forceinline__ float wave_reduce(float v) {
    #pragma unroll
    for (int off = 32; off > 0; off >>= 1) v += __shfl_down(v, off, 64);
    return v;
}

// ---------------------------------------------------------------------------
// K1: all independent precompute.
//   blocks [0,132):   tabs, one block/entry, 4-wave K-split.
//   next 391 blocks:  nib[n], zero {lossp, loss, cnt, done | acc copies}.
//   next 977 blocks:  ei[e] packed edge_states (1 MB L2-class gather table).
// ncopies: 0 = binned mode, >=1 = fallback (zero acc copies).
// ---------------------------------------------------------------------------
#define TAB_BLOCKS  132
#define NODE_BLOCKS 391
#define EI_BLOCKS   977

__global__ __launch_bounds__(256) void fused_pre(
    const int* __restrict__ node_states,
    const int* __restrict__ edge_states,
    const float* __restrict__ node_emb,
    const float* __restrict__ edge_emb,
    const float* __restrict__ cW, const float* __restrict__ cb,
    const float* __restrict__ kW, const float* __restrict__ kb,
    const float* __restrict__ pW, const float* __restrict__ pb,
    const float* __restrict__ pnW, const float* __restrict__ pnb,
    const float* __restrict__ iW, const float* __restrict__ ib,
    const int* __restrict__ tstep,
    uint32_t* __restrict__ acc,
    uint32_t* __restrict__ cnt,
    uint32_t* __restrict__ done,
    uint8_t* __restrict__ ei,
    uint8_t* __restrict__ nib,
    float* __restrict__ tabs,
    float* __restrict__ lossp,
    float* __restrict__ loss_out,
    int ncopies)
{
    const int b = blockIdx.x;

    if (b < TAB_BLOCKS) {
        const int w    = b;                       // 0..131
        const int lane = threadIdx.x & 63;
        const int wv   = threadIdx.x >> 6;
        const float invtau = get_invtau(tstep);
        __shared__ float part[4];

        float p = 0.f;
        if (w < 128) {
            const int isB = w >> 6, h = (w >> 4) & 3, i = w & 15;
            const float* emb = isB ? node_emb : edge_emb;
            const float* cWh = cW + isB * 128 * 128;
            float t0 = 0.f, t1 = 0.f;
            const int l0 = wv * 32;
            #pragma unroll 8
            for (int l = l0; l < l0 + 32; ++l) {
                const float el = emb[i * 128 + l];          // wave-uniform
                t0 += el * cWh[l * 128 + lane];
                t1 += el * cWh[l * 128 + 64 + lane];
            }
            const float* W = (h == 0) ? kW : (h == 1) ? pW : (h == 2) ? pnW : iW;
            const float wd0 = W[2 * lane] - W[2 * lane + 1];
            const float wd1 = W[2 * (lane + 64)] - W[2 * (lane + 64) + 1];
            p = t0 * wd0 + t1 * wd1;
        } else if (wv == 0) {
            const int h = w & 3;
            const float* W = (h == 0) ? kW : (h == 1) ? pW : (h == 2) ? pnW : iW;
            const float wd0 = W[2 * lane] - W[2 * lane + 1];
            const float wd1 = W[2 * (lane + 64)] - W[2 * (lane + 64) + 1];
            p = cb[lane] * wd0 + cb[64 + lane] * wd1;
        }
        p = wave_reduce(p);
        if (lane == 0) part[wv] = p;
        __syncthreads();
        if (threadIdx.x == 0) {
            const float tot = part[0] + part[1] + part[2] + part[3];
            if (w < 128) {
                const int isB = w >> 6, h = (w >> 4) & 3, i = w & 15;
                tabs[isB * 64 + i * 4 + h] = tot * invtau;
            } else {
                const int h = w & 3;
                const float* bb = (h == 0) ? kb : (h == 1) ? pb : (h == 2) ? pnb : ib;
                tabs[128 + h] = (tot + bb[0] - bb[1]) * invtau;
            }
        }
        return;
    }

    if (b < TAB_BLOCKS + NODE_BLOCKS) {
        const int n = (b - TAB_BLOCKS) * 256 + threadIdx.x;
        if (n < 256) lossp[n] = 0.f;
        if (n == 0) *loss_out = 0.f;
        if (ncopies == 0) {
            if (n < NP) cnt[n] = 0u;
            if (n >= 32 && n < 32 + NP) done[n - 32] = 0u;
        }
        if (n < N_NODES) {
            vint4 st = __builtin_nontemporal_load(&((const vint4*)node_states)[n]);
            nib[n] = (uint8_t)(st.x + 2 * st.y + 4 * st.z + 8 * st.w);
            for (int k = 0; k < ncopies; ++k) acc[(size_t)k * N_NODES + n] = 0u;
        }
        return;
    }

    // ---- ei packing: 4 edges/thread, streaming NT reads, uint32 write ----
    const int t = (b - TAB_BLOCKS - NODE_BLOCKS) * 256 + threadIdx.x;
    if (t < N_EDGES / 4) {
        const vint4* esp = (const vint4*)edge_states + 4 * t;
        vint4 e0 = __builtin_nontemporal_load(esp + 0);
        vint4 e1 = __builtin_nontemporal_load(esp + 1);
        vint4 e2 = __builtin_nontemporal_load(esp + 2);
        vint4 e3 = __builtin_nontemporal_load(esp + 3);
        const uint32_t i0 = e0.x + 2 * e0.y + 4 * e0.z + 8 * e0.w;
        const uint32_t i1 = e1.x + 2 * e1.y + 4 * e1.z + 8 * e1.w;
        const uint32_t i2 = e2.x + 2 * e2.y + 4 * e2.z + 8 * e2.w;
        const uint32_t i3 = e3.x + 2 * e3.y + 4 * e3.z + 8 * e3.w;
        ((uint32_t*)ei)[t] = i0 | (i1 << 8) | (i2 << 16) | (i3 << 24);
    }
}

// ---------------------------------------------------------------------------
// K2a (binned): 8 edges/thread, 440 blocks, ticket-first compaction.
// ---------------------------------------------------------------------------
#define EPT 8
__global__ __launch_bounds__(256) void edge_compact(
    const float* __restrict__ s,
    const int* __restrict__ src,
    const int* __restrict__ dst,
    const int* __restrict__ brev,
    const uint8_t* __restrict__ ei,
    const uint8_t* __restrict__ nib,
    const float* __restrict__ tabs,
    const float* __restrict__ target,
    uint32_t* __restrict__ cnt,
    u64* __restrict__ pairs,
    float* __restrict__ lossp,
    float* __restrict__ out)
{
    __shared__ float4 sf[33];
    __shared__ uint32_t lbase[NP], loff[NP];
    const int tid = threadIdx.x;
    if (tid < 33) sf[tid] = ((const float4*)tabs)[tid];
    if (tid < NP) loff[tid] = 0u;
    __syncthreads();

    const int t = blockIdx.x * 256 + tid;          // 0 .. 112639
    const bool active = (t < N_NONLOOP / EPT);     // 112500
    float lsum = 0.f;
    float    ov[EPT], av[EPT];
    int      pj[EPT];
    uint32_t kj[EPT], dloc[EPT];
    int g0 = 0;

    if (active) {
        g0 = (N_NODES / 4) + 2 * t;  // two 16B-aligned quads per thread
        const vint4   rva = __builtin_nontemporal_load(&((const vint4*)brev)[g0]);
        const vint4   rvb = __builtin_nontemporal_load(&((const vint4*)brev)[g0 + 1]);
        const vint4   sra = __builtin_nontemporal_load(&((const vint4*)src)[g0]);
        const vint4   srb = __builtin_nontemporal_load(&((const vint4*)src)[g0 + 1]);
        const vint4   dsa = __builtin_nontemporal_load(&((const vint4*)dst)[g0]);
        const vint4   dsb = __builtin_nontemporal_load(&((const vint4*)dst)[g0 + 1]);
        const vfloat4 sva = __builtin_nontemporal_load(&((const vfloat4*)s)[g0]);
        const vfloat4 svb = __builtin_nontemporal_load(&((const vfloat4*)s)[g0 + 1]);
        const vfloat4 tga = __builtin_nontemporal_load(&((const vfloat4*)target)[g0]);
        const vfloat4 tgb = __builtin_nontemporal_load(&((const vfloat4*)target)[g0 + 1]);

        const int rvv[EPT] = {rva.x, rva.y, rva.z, rva.w, rvb.x, rvb.y, rvb.z, rvb.w};
        const int srv[EPT] = {sra.x, sra.y, sra.z, sra.w, srb.x, srb.y, srb.z, srb.w};
        const int dsv[EPT] = {dsa.x, dsa.y, dsa.z, dsa.w, dsb.x, dsb.y, dsb.z, dsb.w};
        const float svv[EPT] = {sva.x, sva.y, sva.z, sva.w, svb.x, svb.y, svb.z, svb.w};
        const float tgv[EPT] = {tga.x, tga.y, tga.z, tga.w, tgb.x, tgb.y, tgb.z, tgb.w};

        int   eidx[EPT], ni[EPT];
        float ss[EPT], sd[EPT];
        #pragma unroll
        for (int j = 0; j < EPT; ++j) {
            eidx[j] = ei[rvv[j]];
            ni[j]   = nib[srv[j]];
            ss[j]   = s[srv[j]];
            sd[j]   = s[dsv[j]];
        }

        const float4 c4 = sf[32];
        #pragma unroll
        for (int j = 0; j < EPT; ++j) {
            const float4 a = sf[eidx[j]];
            const float4 b = sf[16 + ni[j]];
            const float lk  = a.x + b.x + c4.x;
            const float lp  = a.y + b.y + c4.y;
            const float lpn = a.z + b.z + c4.z;
            const float li  = a.w + b.w + c4.w;
            const float pk  = 1.f / (1.f + __expf(-lk));
            const float pp  = 1.f / (1.f + __expf(-lp));
            const float ppn = 1.f / (1.f + __expf(-lpn));
            const float pi  = 1.f / (1.f + __expf(-li));

            const float s_wo = svv[j] - sd[j];
            const float s_w  = s_wo + ss[j];
            av[j] = pp * s_wo + ppn * s_w;

            const uint32_t p = (uint32_t)dsv[j] / (uint32_t)PSZ;
            pj[j]   = (int)p;
            dloc[j] = (uint32_t)dsv[j] - p * (uint32_t)PSZ;

            ov[j] = pi + svv[j] * pk;
            const float d = tgv[j] - ov[j];
            lsum += d * d;
        }

        // ticket-first: final loff == per-block histogram
        #pragma unroll
        for (int j = 0; j < EPT; ++j) kj[j] = atomicAdd(&loff[pj[j]], 1u);
    }

    __syncthreads();
    if (tid < NP) lbase[tid] = atomicAdd(&cnt[tid], loff[tid]);   // global reserve
    __syncthreads();

    if (active) {
        #pragma unroll
        for (int j = 0; j < EPT; ++j) {
            const uint32_t slot = lbase[pj[j]] + kj[j];
            if (slot < PCAP)
                pairs[(size_t)pj[j] * PCAP + slot] =
                    ((u64)dloc[j] << 32) | (uint32_t)__float_as_int(av[j]);
        }
        vfloat4 o4a = {ov[0], ov[1], ov[2], ov[3]};
        vfloat4 o4b = {ov[4], ov[5], ov[6], ov[7]};
        __builtin_nontemporal_store(o4a, &((vfloat4*)out)[g0]);
        __builtin_nontemporal_store(o4b, &((vfloat4*)out)[g0 + 1]);
    }

    lsum = wave_reduce(lsum);
    if ((tid & 63) == 0)
        atomicAdd(&lossp[(blockIdx.x & 15) * 16], lsum);          // 16 spread cells
}

// ---------------------------------------------------------------------------
// K2b (fused accumulate + finalize, round 7): 256 blocks = NP x GOWN.
// Phase 1: block (p,r) LDS-accumulates its pair chunk, writes partial row.
// Sync:    release fetch_add on done[p]; spin-acquire until all GOWN arrive
//          (agent-scope acquire invalidates this XCD's L2 -> cross-XCD safe).
//          All 256 blocks are co-resident (25.7KB LDS -> 1 block/CU), so the
//          spin cannot starve an unlaunched producer.
// Phase 2: the GOWN blocks of partition p cooperatively finalize its 6250
//          loop-edge nodes (NCHUNK each): out[n] = pi + s[n]*(pk+ppn) + a16.
// Saves one dispatch+gap and overlaps finalize with late accumulation.
// ---------------------------------------------------------------------------
__global__ __launch_bounds__(256) void bin_fin(
    const u64* __restrict__ pairs,
    const uint32_t* __restrict__ cnt,
    uint32_t* __restrict__ done,
    float* __restrict__ partials,
    const float* __restrict__ s,
    const int* __restrict__ brev,
    const uint8_t* __restrict__ ei,
    const uint8_t* __restrict__ nib,
    const float* __restrict__ tabs,
    const float* __restrict__ target,
    const float* __restrict__ lossp,
    float* __restrict__ out,
    float* __restrict__ loss_out)
{
    __shared__ float part[PROW];
    __shared__ float4 sf[33];
    const int tid = threadIdx.x;
    const int p = blockIdx.x >> 4, r = blockIdx.x & 15;

    if (tid < 33) sf[tid] = ((const float4*)tabs)[tid];
    for (int k = tid; k < PROW; k += 256) part[k] = 0.f;
    __syncthreads();

    // ---- phase 1: accumulate my chunk of partition p's pair stream ----
    uint32_t c = cnt[p];
    if (c > PCAP) c = PCAP;
    const uint32_t chunk = (c + GOWN - 1) / GOWN;
    const uint32_t lo = r * chunk;
    uint32_t hi = lo + chunk;
    if (hi > c) hi = c;

    const u64* pp = pairs + (size_t)p * PCAP;
    for (uint32_t i = lo + tid; i < hi; i += 256) {
        const u64 v = pp[i];
        atomicAdd(&part[(uint32_t)(v >> 32)], __int_as_float((int)(uint32_t)v));
    }
    __syncthreads();

    float* row = partials + (size_t)blockIdx.x * PROW;
    for (int k = tid; k < PSZ; k += 256) row[k] = part[k];

    // ---- inter-block sync within partition p (release/acquire, agent) ----
    __syncthreads();
    if (tid == 0) {
        __hip_atomic_fetch_add(&done[p], 1u, __ATOMIC_RELEASE,
                               __HIP_MEMORY_SCOPE_AGENT);
        while (__hip_atomic_load(&done[p], __ATOMIC_ACQUIRE,
                                 __HIP_MEMORY_SCOPE_AGENT) < GOWN)
            __builtin_amdgcn_s_sleep(8);
    }
    __syncthreads();

    // ---- phase 2: finalize nodes [p*PSZ + r*NCHUNK, +NCHUNK) ----
    const int klo = r * NCHUNK;
    const int khi = (klo + NCHUNK < PSZ) ? klo + NCHUNK : PSZ;
    const float* prp = partials + (size_t)p * GOWN * PROW;
    float sq = 0.f;

    for (int k = klo + tid; k < khi; k += 256) {
        const int n = p * PSZ + k;
        const int  eidx = ei[brev[n]];
        const int  ni   = nib[n];
        const float sv  = s[n];

        float a16 = 0.f;
        #pragma unroll
        for (int rr = 0; rr < GOWN; ++rr) a16 += prp[(size_t)rr * PROW + k];

        const float4 a  = sf[eidx];
        const float4 b  = sf[16 + ni];
        const float4 c4 = sf[32];
        const float lk  = a.x + b.x + c4.x;
        const float lpn = a.z + b.z + c4.z;
        const float li  = a.w + b.w + c4.w;
        const float pk  = 1.f / (1.f + __expf(-lk));
        const float ppn = 1.f / (1.f + __expf(-lpn));
        const float pi  = 1.f / (1.f + __expf(-li));

        const float v = pi + sv * (pk + ppn) + a16;
        out[n] = v;
        const float d = target[n] - v;
        sq += d * d;
    }

    sq = wave_reduce(sq);
    __shared__ float wsum[4];
    const int lane = tid & 63, wid = tid >> 6;
    if (lane == 0) wsum[wid] = sq;
    __syncthreads();
    if (tid == 0) {
        float tot = (wsum[0] + wsum[1] + wsum[2] + wsum[3]) * (1.0f / (float)N_EDGES);
        if (blockIdx.x == 0) {
            #pragma unroll
            for (int cix = 0; cix < 16; ++cix)
                tot += lossp[cix * 16] * (1.0f / (float)N_EDGES);
        }
        atomicAdd(loss_out, tot);
    }
}

// ---------------------------------------------------------------------------
// Fallback path (round-3 verified): per-XCD u32 Q20 atomics / device-scope.
// ---------------------------------------------------------------------------
template<int MODE>
__global__ __launch_bounds__(256) void edge_kernel(
    const float* __restrict__ s,
    const int* __restrict__ src,
    const int* __restrict__ dst,
    const int* __restrict__ brev,
    const uint8_t* __restrict__ ei,
    const uint8_t* __restrict__ nib,
    const float* __restrict__ tabs,
    const float* __restrict__ target,
    uint32_t* __restrict__ acc,
    float* __restrict__ lossp,
    float* __restrict__ out,
    float* __restrict__ loss_out)
{
    __shared__ float4 sf[MODE ? 160 : 33];
    if (threadIdx.x < 33) sf[threadIdx.x] = ((const float4*)tabs)[threadIdx.x];
    __syncthreads();

    int xcc = 0;
    uint32_t* accx = acc;
    if (MODE == 1) {
        xcc  = get_xcc();
        accx = acc + (size_t)xcc * N_NODES;
    }

    const int t = blockIdx.x * blockDim.x + threadIdx.x;
    const bool active = (t < N_NONLOOP / 4);
    float lsum = 0.f;
    float ov[4];
    int   iv[4];
    int   dsv[4];
    int   g = 0;

    if (active) {
        g = (N_NODES / 4) + t;
        const vint4   rv = __builtin_nontemporal_load(&((const vint4*)brev)[g]);
        const vint4   sr = __builtin_nontemporal_load(&((const vint4*)src)[g]);
        const vint4   ds = __builtin_nontemporal_load(&((const vint4*)dst)[g]);
        const vfloat4 sv = __builtin_nontemporal_load(&((const vfloat4*)s)[g]);
        const vfloat4 tg = __builtin_nontemporal_load(&((const vfloat4*)target)[g]);

        const int rvv[4] = {rv.x, rv.y, rv.z, rv.w};
        const int srv[4] = {sr.x, sr.y, sr.z, sr.w};
        dsv[0] = ds.x; dsv[1] = ds.y; dsv[2] = ds.z; dsv[3] = ds.w;
        const float svv[4] = {sv.x, sv.y, sv.z, sv.w};
        const float tgv[4] = {tg.x, tg.y, tg.z, tg.w};

        int   eidx[4], ni[4];
        float ss[4], sd[4];
        #pragma unroll
        for (int j = 0; j < 4; ++j) {
            eidx[j] = ei[rvv[j]];
            ni[j]   = nib[srv[j]];
            ss[j]   = s[srv[j]];
            sd[j]   = s[dsv[j]];
        }

        const float4 c4 = sf[32];
        #pragma unroll
        for (int j = 0; j < 4; ++j) {
            const float4 a = sf[eidx[j]];
            const float4 b = sf[16 + ni[j]];
            const float lk  = a.x + b.x + c4.x;
            const float lp  = a.y + b.y + c4.y;
            const float lpn = a.z + b.z + c4.z;
            const float li  = a.w + b.w + c4.w;
            const float pk  = 1.f / (1.f + __expf(-lk));
            const float pp  = 1.f / (1.f + __expf(-lp));
            const float ppn = 1.f / (1.f + __expf(-lpn));
            const float pi  = 1.f / (1.f + __expf(-li));

            const float s_wo = svv[j] - sd[j];
            const float s_w  = s_wo + ss[j];
            iv[j] = __float2int_rn((pp * s_wo + ppn * s_w) * ACC_SCALE);

            ov[j] = pi + svv[j] * pk;
            const float d = tgv[j] - ov[j];
            lsum += d * d;
        }
    }

    lsum = wave_reduce(lsum);
    __shared__ float wsum[4];
    const int lane = threadIdx.x & 63, wid = threadIdx.x >> 6;
    if (lane == 0) wsum[wid] = lsum;
    __syncthreads();
    if (threadIdx.x == 0) {
        const float tot = (wsum[0] + wsum[1] + wsum[2] + wsum[3]) * (1.0f / (float)N_EDGES);
        if (MODE == 1) l2_atomic_add_f32(&lossp[xcc * 32], tot);
        else           atomicAdd(loss_out, tot);
    }

    if (active) {
        #pragma unroll
        for (int j = 0; j < 4; ++j) {
            if (MODE == 1) l2_atomic_add_u32(&accx[dsv[j]], (uint32_t)iv[j]);
            else           atomicAdd((unsigned int*)&acc[dsv[j]], (unsigned int)iv[j]);
        }
        vfloat4 o4 = {ov[0], ov[1], ov[2], ov[3]};
        __builtin_nontemporal_store(o4, &((vfloat4*)out)[g]);
    }
}

template<int NC>
__global__ __launch_bounds__(256) void finalize_nodes(
    const float* __restrict__ s,
    const int* __restrict__ brev,
    const uint8_t* __restrict__ ei,
    const uint8_t* __restrict__ nib,
    const float* __restrict__ tabs,
    const float* __restrict__ target,
    const uint32_t* __restrict__ acc,
    const float* __restrict__ lossp,
    float* __restrict__ out,
    float* __restrict__ loss_out)
{
    __shared__ float4 sf[33];
    if (threadIdx.x < 33) sf[threadIdx.x] = ((const float4*)tabs)[threadIdx.x];
    __syncthreads();

    const int n = blockIdx.x * blockDim.x + threadIdx.x;
    const bool active = (n < N_NODES);
    float sq = 0.f, v = 0.f;
    if (active) {
        const int  eidx = ei[brev[n]];
        const int  ni   = nib[n];
        const float sv  = s[n];

        uint32_t asum = 0u;
        #pragma unroll
        for (int k = 0; k < NC; ++k) asum += acc[(size_t)k * N_NODES + n];
        const float a8 = (float)(int)asum * ACC_INV;

        const float4 a  = sf[eidx];
        const float4 b  = sf[16 + ni];
        const float4 c4 = sf[32];
        const float lk  = a.x + b.x + c4.x;
        const float lpn = a.z + b.z + c4.z;
        const float li  = a.w + b.w + c4.w;
        const float pk  = 1.f / (1.f + __expf(-lk));
        const float ppn = 1.f / (1.f + __expf(-lpn));
        const float pi  = 1.f / (1.f + __expf(-li));

        v = pi + sv * (pk + ppn) + a8;
        const float d = target[n] - v;
        sq = d * d;
    }
    sq = wave_reduce(sq);
    __shared__ float wsum[4];
    const int lane = threadIdx.x & 63, wid = threadIdx.x >> 6;
    if (lane == 0) wsum[wid] = sq;
    __syncthreads();
    if (threadIdx.x == 0) {
        float tot = (wsum[0] + wsum[1] + wsum[2] + wsum[3]) * (1.0f / (float)N_EDGES);
        if (blockIdx.x == 0) {
            #pragma unroll
            for (int k = 0; k < NXCD; ++k) tot += lossp[k * 32];
        }
        atomicAdd(loss_out, tot);
    }
    if (active) out[n] = v;
}

extern "C" void kernel_launch(void* const* d_in, const int* in_sizes, int n_in,
                              void* d_out, int out_size, void* d_ws, size_t ws_size,
                              hipStream_t stream) {
    const int*   node_states   = (const int*)d_in[0];
    const int*   edge_states   = (const int*)d_in[1];
    const float* scalars       = (const float*)d_in[2];
    const int*   edge_index    = (const int*)d_in[3];
    const int*   brev          = (const int*)d_in[4];
    const float* batch_scalars = (const float*)d_in[5];
    // d_in[6] = processor_step (batch axis-1 size 1 -> index 0)
    const int*   training_step = (const int*)d_in[7];
    const float* node_emb  = (const float*)d_in[8];
    const float* edge_emb  = (const float*)d_in[9];
    const float* combine_W = (const float*)d_in[10];
    const float* combine_b = (const float*)d_in[11];
    const float* keep_W  = (const float*)d_in[12];
    const float* keep_b  = (const float*)d_in[13];
    const float* push_W  = (const float*)d_in[14];
    const float* push_b  = (const float*)d_in[15];
    const float* pushn_W = (const float*)d_in[16];
    const float* pushn_b = (const float*)d_in[17];
    const float* inc_W   = (const float*)d_in[18];
    const float* inc_b   = (const float*)d_in[19];

    float* out = (float*)d_out;  // [0..E) new_scalars, [E] loss

    const int* srcp = edge_index;
    const int* dstp = edge_index + N_EDGES;

    // ---- workspace budgets ----
    const size_t PAIRS_B    = (size_t)NP * PCAP * 8;        // 7,864,320
    const size_t PARTIALS_B = (size_t)NP * GOWN * PROW * 4; // 6,422,528
    const size_t need_binned = 3072 + PAIRS_B + PARTIALS_B + N_EDGES + N_NODES; // ~14.7 MB
    const size_t need_scoped = 2048 + (size_t)NXCD * N_NODES * 4 + N_EDGES + N_NODES; // ~4.3 MB

    char* ws = (char*)d_ws;

    if (ws_size >= need_binned) {
        // ---- binned (atomic-free accumulation) path ----
        float*    tabs     = (float*)ws;                         // 1 KiB
        float*    lossp    = (float*)(ws + 1024);                // 1 KiB (16 cells x 64B)
        uint32_t* cnt      = (uint32_t*)(ws + 2048);             // 64 B
        uint32_t* done     = (uint32_t*)(ws + 2048 + 512);       // 64 B (within 1 KiB pad)
        u64*      pairs    = (u64*)(ws + 3072);                  // 7.86 MB
        float*    partials = (float*)(ws + 3072 + PAIRS_B);      // 6.42 MB
        uint8_t*  ei       = (uint8_t*)(ws + 3072 + PAIRS_B + PARTIALS_B);
        uint8_t*  nib      = ei + N_EDGES;

        fused_pre<<<TAB_BLOCKS + NODE_BLOCKS + EI_BLOCKS, 256, 0, stream>>>(
            node_states, edge_states, node_emb, edge_emb,
            combine_W, combine_b, keep_W, keep_b, push_W, push_b,
            pushn_W, pushn_b, inc_W, inc_b, training_step,
            nullptr, cnt, done, ei, nib, tabs, lossp, out + N_EDGES, 0);

        const int ethreads8 = N_NONLOOP / EPT;   // 112500
        edge_compact<<<(ethreads8 + 255) / 256, 256, 0, stream>>>(
            scalars, srcp, dstp, brev, ei, nib, tabs, batch_scalars,
            cnt, pairs, lossp, out);

        bin_fin<<<NP * GOWN, 256, 0, stream>>>(
            pairs, cnt, done, partials, scalars, brev, ei, nib, tabs,
            batch_scalars, lossp, out, out + N_EDGES);
    } else {
        const bool scoped = (ws_size >= need_scoped);
        const int nc = scoped ? NXCD : 1;

        float*    tabs  = (float*)ws;
        float*    lossp = (float*)(ws + 1024);
        uint32_t* acc   = (uint32_t*)(ws + 2048);
        uint8_t*  ei    = (uint8_t*)(ws + 2048 + (size_t)nc * N_NODES * 4);
        uint8_t*  nib   = ei + N_EDGES;

        fused_pre<<<TAB_BLOCKS + NODE_BLOCKS + EI_BLOCKS, 256, 0, stream>>>(
            node_states, edge_states, node_emb, edge_emb,
            combine_W, combine_b, keep_W, keep_b, push_W, push_b,
            pushn_W, pushn_b, inc_W, inc_b, training_step,
            acc, nullptr, nullptr, ei, nib, tabs, lossp, out + N_EDGES, nc);

        const int ethreads = N_NONLOOP / 4;   // 225000
        const int eblocks  = (ethreads + 255) / 256;
        if (scoped) {
            edge_kernel<1><<<eblocks, 256, 0, stream>>>(
                scalars, srcp, dstp, brev, ei, nib, tabs, batch_scalars,
                acc, lossp, out, out + N_EDGES);
            finalize_nodes<NXCD><<<(N_NODES + 255) / 256, 256, 0, stream>>>(
                scalars, brev, ei, nib, tabs, batch_scalars, acc, lossp,
                out, out + N_EDGES);
        } else {
            edge_kernel<0><<<eblocks, 256, 0, stream>>>(
                scalars, srcp, dstp, brev, ei, nib, tabs, batch_scalars,
                acc, lossp, out, out + N_EDGES);
            finalize_nodes<1><<<(N_NODES + 255) / 256, 256, 0, stream>>>(
                scalars, brev, ei, nib, tabs, batch_scalars, acc, lossp,
                out, out + N_EDGES);
        }
    }
}

// Round 8
// 155.835 us; speedup vs baseline: 1.0490x; 1.0490x over previous
//
#include <hip/hip_runtime.h>
#include <math.h>
#include <stdint.h>

#define N_NODES 100000
#define N_EDGES 1000000
#define N_NONLOOP (N_EDGES - N_NODES)          // 900000 edges needing accumulation
#define NXCD 8

// ---- binned-accumulation geometry (round-5 best: 256 accumulate blocks) ----
#define NP    16         // node partitions
#define PSZ   6250       // nodes per partition (100000/16)
#define PCAP  61440      // slot capacity per partition (mean 56.25K, +22 sigma)
#define GOWN  16         // owner blocks per partition -> 256 blocks
#define PROW  6272       // padded partial-row stride (floats, 64B-aligned)

// Q20 fixed-point (fallback path only)
#define ACC_SCALE   1048576.0f
#define ACC_INV     (1.0f / 1048576.0f)

typedef float  vfloat4 __attribute__((ext_vector_type(4)));
typedef int    vint4   __attribute__((ext_vector_type(4)));
typedef unsigned long long u64;

// HW_REG_XCC_ID = 20 on gfx940+; read bits [3:0]
#define XCC_ID_HWREG (20 | ((4 - 1) << 11))
__device__ __forceinline__ int get_xcc() {
    return __builtin_amdgcn_s_getreg(XCC_ID_HWREG) & (NXCD - 1);
}
__device__ __forceinline__ void l2_atomic_add_u32(uint32_t* p, uint32_t v) {
    asm volatile("global_atomic_add %0, %1, off" :: "v"(p), "v"(v) : "memory");
}
__device__ __forceinline__ void l2_atomic_add_f32(float* p, float v) {
    asm volatile("global_atomic_add_f32 %0, %1, off" :: "v"(p), "v"(v) : "memory");
}

__device__ __forceinline__ float get_invtau(const int* __restrict__ training_step) {
    int step = training_step[0];
    float tau;
    if (step == -1) {
        tau = 0.1f;  // TEMP_EVAL
    } else {
        float frac = fminf((float)step / 10000.0f, 1.0f);
        tau = 1.0f + (0.1f - 1.0f) * frac;
    }
    return 1.0f / tau;
}

__device__ __forceinline__ float wave_reduce(float v) {
    #pragma unroll
    for (int off = 32; off > 0; off >>= 1) v += __shfl_down(v, off, 64);
    return v;
}

// ---------------------------------------------------------------------------
// K1: all independent precompute.
//   blocks [0,132):   tabs, one block/entry, 4-wave K-split.
//   next 391 blocks:  nib[n], zero {lossp, loss, cnt | acc copies}.
//   next 977 blocks:  ei[e] packed edge_states (1 MB L2-class gather table).
// ncopies: 0 = binned mode (zero cnt), >=1 = fallback (zero acc copies).
// ---------------------------------------------------------------------------
#define TAB_BLOCKS  132
#define NODE_BLOCKS 391
#define EI_BLOCKS   977

__global__ __launch_bounds__(256) void fused_pre(
    const int* __restrict__ node_states,
    const int* __restrict__ edge_states,
    const float* __restrict__ node_emb,
    const float* __restrict__ edge_emb,
    const float* __restrict__ cW, const float* __restrict__ cb,
    const float* __restrict__ kW, const float* __restrict__ kb,
    const float* __restrict__ pW, const float* __restrict__ pb,
    const float* __restrict__ pnW, const float* __restrict__ pnb,
    const float* __restrict__ iW, const float* __restrict__ ib,
    const int* __restrict__ tstep,
    uint32_t* __restrict__ acc,
    uint32_t* __restrict__ cnt,
    uint8_t* __restrict__ ei,
    uint8_t* __restrict__ nib,
    float* __restrict__ tabs,
    float* __restrict__ lossp,
    float* __restrict__ loss_out,
    int ncopies)
{
    const int b = blockIdx.x;

    if (b < TAB_BLOCKS) {
        const int w    = b;                       // 0..131
        const int lane = threadIdx.x & 63;
        const int wv   = threadIdx.x >> 6;
        const float invtau = get_invtau(tstep);
        __shared__ float part[4];

        float p = 0.f;
        if (w < 128) {
            const int isB = w >> 6, h = (w >> 4) & 3, i = w & 15;
            const float* emb = isB ? node_emb : edge_emb;
            const float* cWh = cW + isB * 128 * 128;
            float t0 = 0.f, t1 = 0.f;
            const int l0 = wv * 32;
            #pragma unroll 8
            for (int l = l0; l < l0 + 32; ++l) {
                const float el = emb[i * 128 + l];          // wave-uniform
                t0 += el * cWh[l * 128 + lane];
                t1 += el * cWh[l * 128 + 64 + lane];
            }
            const float* W = (h == 0) ? kW : (h == 1) ? pW : (h == 2) ? pnW : iW;
            const float wd0 = W[2 * lane] - W[2 * lane + 1];
            const float wd1 = W[2 * (lane + 64)] - W[2 * (lane + 64) + 1];
            p = t0 * wd0 + t1 * wd1;
        } else if (wv == 0) {
            const int h = w & 3;
            const float* W = (h == 0) ? kW : (h == 1) ? pW : (h == 2) ? pnW : iW;
            const float wd0 = W[2 * lane] - W[2 * lane + 1];
            const float wd1 = W[2 * (lane + 64)] - W[2 * (lane + 64) + 1];
            p = cb[lane] * wd0 + cb[64 + lane] * wd1;
        }
        p = wave_reduce(p);
        if (lane == 0) part[wv] = p;
        __syncthreads();
        if (threadIdx.x == 0) {
            const float tot = part[0] + part[1] + part[2] + part[3];
            if (w < 128) {
                const int isB = w >> 6, h = (w >> 4) & 3, i = w & 15;
                tabs[isB * 64 + i * 4 + h] = tot * invtau;
            } else {
                const int h = w & 3;
                const float* bb = (h == 0) ? kb : (h == 1) ? pb : (h == 2) ? pnb : ib;
                tabs[128 + h] = (tot + bb[0] - bb[1]) * invtau;
            }
        }
        return;
    }

    if (b < TAB_BLOCKS + NODE_BLOCKS) {
        const int n = (b - TAB_BLOCKS) * 256 + threadIdx.x;
        if (n < 256) lossp[n] = 0.f;
        if (n == 0) *loss_out = 0.f;
        if (ncopies == 0) {
            if (n < NP) cnt[n] = 0u;
        }
        if (n < N_NODES) {
            vint4 st = __builtin_nontemporal_load(&((const vint4*)node_states)[n]);
            nib[n] = (uint8_t)(st.x + 2 * st.y + 4 * st.z + 8 * st.w);
            for (int k = 0; k < ncopies; ++k) acc[(size_t)k * N_NODES + n] = 0u;
        }
        return;
    }

    // ---- ei packing: 4 edges/thread, streaming NT reads, uint32 write ----
    const int t = (b - TAB_BLOCKS - NODE_BLOCKS) * 256 + threadIdx.x;
    if (t < N_EDGES / 4) {
        const vint4* esp = (const vint4*)edge_states + 4 * t;
        vint4 e0 = __builtin_nontemporal_load(esp + 0);
        vint4 e1 = __builtin_nontemporal_load(esp + 1);
        vint4 e2 = __builtin_nontemporal_load(esp + 2);
        vint4 e3 = __builtin_nontemporal_load(esp + 3);
        const uint32_t i0 = e0.x + 2 * e0.y + 4 * e0.z + 8 * e0.w;
        const uint32_t i1 = e1.x + 2 * e1.y + 4 * e1.z + 8 * e1.w;
        const uint32_t i2 = e2.x + 2 * e2.y + 4 * e2.z + 8 * e2.w;
        const uint32_t i3 = e3.x + 2 * e3.y + 4 * e3.z + 8 * e3.w;
        ((uint32_t*)ei)[t] = i0 | (i1 << 8) | (i2 << 16) | (i3 << 24);
    }
}

// ---------------------------------------------------------------------------
// K2a (binned): 8 edges/thread, 440 blocks, ticket-first compaction.
// No per-edge device atomics.
// ---------------------------------------------------------------------------
#define EPT 8
__global__ __launch_bounds__(256) void edge_compact(
    const float* __restrict__ s,
    const int* __restrict__ src,
    const int* __restrict__ dst,
    const int* __restrict__ brev,
    const uint8_t* __restrict__ ei,
    const uint8_t* __restrict__ nib,
    const float* __restrict__ tabs,
    const float* __restrict__ target,
    uint32_t* __restrict__ cnt,
    u64* __restrict__ pairs,
    float* __restrict__ lossp,
    float* __restrict__ out)
{
    __shared__ float4 sf[33];
    __shared__ uint32_t lbase[NP], loff[NP];
    const int tid = threadIdx.x;
    if (tid < 33) sf[tid] = ((const float4*)tabs)[tid];
    if (tid < NP) loff[tid] = 0u;
    __syncthreads();

    const int t = blockIdx.x * 256 + tid;          // 0 .. 112639
    const bool active = (t < N_NONLOOP / EPT);     // 112500
    float lsum = 0.f;
    float    ov[EPT], av[EPT];
    int      pj[EPT];
    uint32_t kj[EPT], dloc[EPT];
    int g0 = 0;

    if (active) {
        g0 = (N_NODES / 4) + 2 * t;  // two 16B-aligned quads per thread
        const vint4   rva = __builtin_nontemporal_load(&((const vint4*)brev)[g0]);
        const vint4   rvb = __builtin_nontemporal_load(&((const vint4*)brev)[g0 + 1]);
        const vint4   sra = __builtin_nontemporal_load(&((const vint4*)src)[g0]);
        const vint4   srb = __builtin_nontemporal_load(&((const vint4*)src)[g0 + 1]);
        const vint4   dsa = __builtin_nontemporal_load(&((const vint4*)dst)[g0]);
        const vint4   dsb = __builtin_nontemporal_load(&((const vint4*)dst)[g0 + 1]);
        const vfloat4 sva = __builtin_nontemporal_load(&((const vfloat4*)s)[g0]);
        const vfloat4 svb = __builtin_nontemporal_load(&((const vfloat4*)s)[g0 + 1]);
        const vfloat4 tga = __builtin_nontemporal_load(&((const vfloat4*)target)[g0]);
        const vfloat4 tgb = __builtin_nontemporal_load(&((const vfloat4*)target)[g0 + 1]);

        const int rvv[EPT] = {rva.x, rva.y, rva.z, rva.w, rvb.x, rvb.y, rvb.z, rvb.w};
        const int srv[EPT] = {sra.x, sra.y, sra.z, sra.w, srb.x, srb.y, srb.z, srb.w};
        const int dsv[EPT] = {dsa.x, dsa.y, dsa.z, dsa.w, dsb.x, dsb.y, dsb.z, dsb.w};
        const float svv[EPT] = {sva.x, sva.y, sva.z, sva.w, svb.x, svb.y, svb.z, svb.w};
        const float tgv[EPT] = {tga.x, tga.y, tga.z, tga.w, tgb.x, tgb.y, tgb.z, tgb.w};

        // 32 independent L2-class gathers issued up front
        int   eidx[EPT], ni[EPT];
        float ss[EPT], sd[EPT];
        #pragma unroll
        for (int j = 0; j < EPT; ++j) {
            eidx[j] = ei[rvv[j]];
            ni[j]   = nib[srv[j]];
            ss[j]   = s[srv[j]];
            sd[j]   = s[dsv[j]];
        }

        const float4 c4 = sf[32];
        #pragma unroll
        for (int j = 0; j < EPT; ++j) {
            const float4 a = sf[eidx[j]];
            const float4 b = sf[16 + ni[j]];
            const float lk  = a.x + b.x + c4.x;
            const float lp  = a.y + b.y + c4.y;
            const float lpn = a.z + b.z + c4.z;
            const float li  = a.w + b.w + c4.w;
            const float pk  = 1.f / (1.f + __expf(-lk));
            const float pp  = 1.f / (1.f + __expf(-lp));
            const float ppn = 1.f / (1.f + __expf(-lpn));
            const float pi  = 1.f / (1.f + __expf(-li));

            const float s_wo = svv[j] - sd[j];
            const float s_w  = s_wo + ss[j];
            av[j] = pp * s_wo + ppn * s_w;

            const uint32_t p = (uint32_t)dsv[j] / (uint32_t)PSZ;
            pj[j]   = (int)p;
            dloc[j] = (uint32_t)dsv[j] - p * (uint32_t)PSZ;

            ov[j] = pi + svv[j] * pk;
            const float d = tgv[j] - ov[j];
            lsum += d * d;
        }

        // ticket-first: final loff == per-block histogram
        #pragma unroll
        for (int j = 0; j < EPT; ++j) kj[j] = atomicAdd(&loff[pj[j]], 1u);
    }

    __syncthreads();
    if (tid < NP) lbase[tid] = atomicAdd(&cnt[tid], loff[tid]);   // global reserve
    __syncthreads();

    if (active) {
        #pragma unroll
        for (int j = 0; j < EPT; ++j) {
            const uint32_t slot = lbase[pj[j]] + kj[j];
            if (slot < PCAP)
                pairs[(size_t)pj[j] * PCAP + slot] =
                    ((u64)dloc[j] << 32) | (uint32_t)__float_as_int(av[j]);
        }
        vfloat4 o4a = {ov[0], ov[1], ov[2], ov[3]};
        vfloat4 o4b = {ov[4], ov[5], ov[6], ov[7]};
        __builtin_nontemporal_store(o4a, &((vfloat4*)out)[g0]);
        __builtin_nontemporal_store(o4b, &((vfloat4*)out)[g0 + 1]);
    }

    lsum = wave_reduce(lsum);
    if ((tid & 63) == 0)
        atomicAdd(&lossp[(blockIdx.x & 15) * 16], lsum);          // 16 spread cells
}

// ---------------------------------------------------------------------------
// K2b (binned): 16 partitions x 16 owner blocks = 256 blocks (1/CU). Each
// block LDS-accumulates its ~3.5K-pair chunk into a 25KB LDS array, flushes
// one coalesced partial row. LDS atomics only -- zero coherence traffic.
// NOTE (round 7): fusing finalize into this kernel via a per-partition
// spin-wait REGRESSED +6us (straggler serialization beats the ~2us dispatch
// gap). Keep split.
// ---------------------------------------------------------------------------
__global__ __launch_bounds__(256) void bin_accum(
    const u64* __restrict__ pairs,
    const uint32_t* __restrict__ cnt,
    float* __restrict__ partials)
{
    __shared__ float part[PROW];
    const int tid = threadIdx.x;
    const int p = blockIdx.x >> 4, r = blockIdx.x & 15;

    for (int k = tid; k < PROW; k += 256) part[k] = 0.f;
    __syncthreads();

    uint32_t c = cnt[p];
    if (c > PCAP) c = PCAP;
    const uint32_t chunk = (c + GOWN - 1) / GOWN;
    const uint32_t lo = r * chunk;
    uint32_t hi = lo + chunk;
    if (hi > c) hi = c;

    const u64* pp = pairs + (size_t)p * PCAP;
    for (uint32_t i = lo + tid; i < hi; i += 256) {
        const u64 v = pp[i];
        atomicAdd(&part[(uint32_t)(v >> 32)], __int_as_float((int)(uint32_t)v));
    }
    __syncthreads();

    float* row = partials + (size_t)blockIdx.x * PROW;
    for (int k = tid; k < PSZ; k += 256) row[k] = part[k];
}

// ---------------------------------------------------------------------------
// K3 (binned): out[n] = pi + s[n]*(pk+ppn) + sum_r partials[(p*16+r)][off].
// Block 0 folds the 16 edge-loss cells.
// ---------------------------------------------------------------------------
__global__ __launch_bounds__(256) void finalize_binned(
    const float* __restrict__ s,
    const int* __restrict__ brev,
    const uint8_t* __restrict__ ei,
    const uint8_t* __restrict__ nib,
    const float* __restrict__ tabs,
    const float* __restrict__ target,
    const float* __restrict__ partials,
    const float* __restrict__ lossp,
    float* __restrict__ out,
    float* __restrict__ loss_out)
{
    __shared__ float4 sf[33];
    if (threadIdx.x < 33) sf[threadIdx.x] = ((const float4*)tabs)[threadIdx.x];
    __syncthreads();

    const int n = blockIdx.x * blockDim.x + threadIdx.x;
    const bool active = (n < N_NODES);
    float sq = 0.f, v = 0.f;
    if (active) {
        const int  eidx = ei[brev[n]];
        const int  ni   = nib[n];
        const float sv  = s[n];

        const uint32_t p   = (uint32_t)n / (uint32_t)PSZ;
        const uint32_t off = (uint32_t)n - p * PSZ;
        const float* pr = partials + (size_t)p * GOWN * PROW + off;
        float a8 = 0.f;
        #pragma unroll
        for (int r = 0; r < GOWN; ++r) a8 += pr[(size_t)r * PROW];

        const float4 a  = sf[eidx];
        const float4 b  = sf[16 + ni];
        const float4 c4 = sf[32];
        const float lk  = a.x + b.x + c4.x;
        const float lpn = a.z + b.z + c4.z;
        const float li  = a.w + b.w + c4.w;
        const float pk  = 1.f / (1.f + __expf(-lk));
        const float ppn = 1.f / (1.f + __expf(-lpn));
        const float pi  = 1.f / (1.f + __expf(-li));

        v = pi + sv * (pk + ppn) + a8;
        const float d = target[n] - v;
        sq = d * d;
    }
    sq = wave_reduce(sq);
    __shared__ float wsum[4];
    const int lane = threadIdx.x & 63, wid = threadIdx.x >> 6;
    if (lane == 0) wsum[wid] = sq;
    __syncthreads();
    if (threadIdx.x == 0) {
        float tot = (wsum[0] + wsum[1] + wsum[2] + wsum[3]) * (1.0f / (float)N_EDGES);
        if (blockIdx.x == 0) {
            #pragma unroll
            for (int c = 0; c < 16; ++c) tot += lossp[c * 16] * (1.0f / (float)N_EDGES);
        }
        atomicAdd(loss_out, tot);
    }
    if (active) out[n] = v;
}

// ---------------------------------------------------------------------------
// Fallback path (round-3 verified): per-XCD u32 Q20 atomics / device-scope.
// ---------------------------------------------------------------------------
template<int MODE>
__global__ __launch_bounds__(256) void edge_kernel(
    const float* __restrict__ s,
    const int* __restrict__ src,
    const int* __restrict__ dst,
    const int* __restrict__ brev,
    const uint8_t* __restrict__ ei,
    const uint8_t* __restrict__ nib,
    const float* __restrict__ tabs,
    const float* __restrict__ target,
    uint32_t* __restrict__ acc,
    float* __restrict__ lossp,
    float* __restrict__ out,
    float* __restrict__ loss_out)
{
    __shared__ float4 sf[MODE ? 160 : 33];
    if (threadIdx.x < 33) sf[threadIdx.x] = ((const float4*)tabs)[threadIdx.x];
    __syncthreads();

    int xcc = 0;
    uint32_t* accx = acc;
    if (MODE == 1) {
        xcc  = get_xcc();
        accx = acc + (size_t)xcc * N_NODES;
    }

    const int t = blockIdx.x * blockDim.x + threadIdx.x;
    const bool active = (t < N_NONLOOP / 4);
    float lsum = 0.f;
    float ov[4];
    int   iv[4];
    int   dsv[4];
    int   g = 0;

    if (active) {
        g = (N_NODES / 4) + t;
        const vint4   rv = __builtin_nontemporal_load(&((const vint4*)brev)[g]);
        const vint4   sr = __builtin_nontemporal_load(&((const vint4*)src)[g]);
        const vint4   ds = __builtin_nontemporal_load(&((const vint4*)dst)[g]);
        const vfloat4 sv = __builtin_nontemporal_load(&((const vfloat4*)s)[g]);
        const vfloat4 tg = __builtin_nontemporal_load(&((const vfloat4*)target)[g]);

        const int rvv[4] = {rv.x, rv.y, rv.z, rv.w};
        const int srv[4] = {sr.x, sr.y, sr.z, sr.w};
        dsv[0] = ds.x; dsv[1] = ds.y; dsv[2] = ds.z; dsv[3] = ds.w;
        const float svv[4] = {sv.x, sv.y, sv.z, sv.w};
        const float tgv[4] = {tg.x, tg.y, tg.z, tg.w};

        int   eidx[4], ni[4];
        float ss[4], sd[4];
        #pragma unroll
        for (int j = 0; j < 4; ++j) {
            eidx[j] = ei[rvv[j]];
            ni[j]   = nib[srv[j]];
            ss[j]   = s[srv[j]];
            sd[j]   = s[dsv[j]];
        }

        const float4 c4 = sf[32];
        #pragma unroll
        for (int j = 0; j < 4; ++j) {
            const float4 a = sf[eidx[j]];
            const float4 b = sf[16 + ni[j]];
            const float lk  = a.x + b.x + c4.x;
            const float lp  = a.y + b.y + c4.y;
            const float lpn = a.z + b.z + c4.z;
            const float li  = a.w + b.w + c4.w;
            const float pk  = 1.f / (1.f + __expf(-lk));
            const float pp  = 1.f / (1.f + __expf(-lp));
            const float ppn = 1.f / (1.f + __expf(-lpn));
            const float pi  = 1.f / (1.f + __expf(-li));

            const float s_wo = svv[j] - sd[j];
            const float s_w  = s_wo + ss[j];
            iv[j] = __float2int_rn((pp * s_wo + ppn * s_w) * ACC_SCALE);

            ov[j] = pi + svv[j] * pk;
            const float d = tgv[j] - ov[j];
            lsum += d * d;
        }
    }

    lsum = wave_reduce(lsum);
    __shared__ float wsum[4];
    const int lane = threadIdx.x & 63, wid = threadIdx.x >> 6;
    if (lane == 0) wsum[wid] = lsum;
    __syncthreads();
    if (threadIdx.x == 0) {
        const float tot = (wsum[0] + wsum[1] + wsum[2] + wsum[3]) * (1.0f / (float)N_EDGES);
        if (MODE == 1) l2_atomic_add_f32(&lossp[xcc * 32], tot);
        else           atomicAdd(loss_out, tot);
    }

    if (active) {
        #pragma unroll
        for (int j = 0; j < 4; ++j) {
            if (MODE == 1) l2_atomic_add_u32(&accx[dsv[j]], (uint32_t)iv[j]);
            else           atomicAdd((unsigned int*)&acc[dsv[j]], (unsigned int)iv[j]);
        }
        vfloat4 o4 = {ov[0], ov[1], ov[2], ov[3]};
        __builtin_nontemporal_store(o4, &((vfloat4*)out)[g]);
    }
}

template<int NC>
__global__ __launch_bounds__(256) void finalize_nodes(
    const float* __restrict__ s,
    const int* __restrict__ brev,
    const uint8_t* __restrict__ ei,
    const uint8_t* __restrict__ nib,
    const float* __restrict__ tabs,
    const float* __restrict__ target,
    const uint32_t* __restrict__ acc,
    const float* __restrict__ lossp,
    float* __restrict__ out,
    float* __restrict__ loss_out)
{
    __shared__ float4 sf[33];
    if (threadIdx.x < 33) sf[threadIdx.x] = ((const float4*)tabs)[threadIdx.x];
    __syncthreads();

    const int n = blockIdx.x * blockDim.x + threadIdx.x;
    const bool active = (n < N_NODES);
    float sq = 0.f, v = 0.f;
    if (active) {
        const int  eidx = ei[brev[n]];
        const int  ni   = nib[n];
        const float sv  = s[n];

        uint32_t asum = 0u;
        #pragma unroll
        for (int k = 0; k < NC; ++k) asum += acc[(size_t)k * N_NODES + n];
        const float a8 = (float)(int)asum * ACC_INV;

        const float4 a  = sf[eidx];
        const float4 b  = sf[16 + ni];
        const float4 c4 = sf[32];
        const float lk  = a.x + b.x + c4.x;
        const float lpn = a.z + b.z + c4.z;
        const float li  = a.w + b.w + c4.w;
        const float pk  = 1.f / (1.f + __expf(-lk));
        const float ppn = 1.f / (1.f + __expf(-lpn));
        const float pi  = 1.f / (1.f + __expf(-li));

        v = pi + sv * (pk + ppn) + a8;
        const float d = target[n] - v;
        sq = d * d;
    }
    sq = wave_reduce(sq);
    __shared__ float wsum[4];
    const int lane = threadIdx.x & 63, wid = threadIdx.x >> 6;
    if (lane == 0) wsum[wid] = sq;
    __syncthreads();
    if (threadIdx.x == 0) {
        float tot = (wsum[0] + wsum[1] + wsum[2] + wsum[3]) * (1.0f / (float)N_EDGES);
        if (blockIdx.x == 0) {
            #pragma unroll
            for (int k = 0; k < NXCD; ++k) tot += lossp[k * 32];
        }
        atomicAdd(loss_out, tot);
    }
    if (active) out[n] = v;
}

extern "C" void kernel_launch(void* const* d_in, const int* in_sizes, int n_in,
                              void* d_out, int out_size, void* d_ws, size_t ws_size,
                              hipStream_t stream) {
    const int*   node_states   = (const int*)d_in[0];
    const int*   edge_states   = (const int*)d_in[1];
    const float* scalars       = (const float*)d_in[2];
    const int*   edge_index    = (const int*)d_in[3];
    const int*   brev          = (const int*)d_in[4];
    const float* batch_scalars = (const float*)d_in[5];
    // d_in[6] = processor_step (batch axis-1 size 1 -> index 0)
    const int*   training_step = (const int*)d_in[7];
    const float* node_emb  = (const float*)d_in[8];
    const float* edge_emb  = (const float*)d_in[9];
    const float* combine_W = (const float*)d_in[10];
    const float* combine_b = (const float*)d_in[11];
    const float* keep_W  = (const float*)d_in[12];
    const float* keep_b  = (const float*)d_in[13];
    const float* push_W  = (const float*)d_in[14];
    const float* push_b  = (const float*)d_in[15];
    const float* pushn_W = (const float*)d_in[16];
    const float* pushn_b = (const float*)d_in[17];
    const float* inc_W   = (const float*)d_in[18];
    const float* inc_b   = (const float*)d_in[19];

    float* out = (float*)d_out;  // [0..E) new_scalars, [E] loss

    const int* srcp = edge_index;
    const int* dstp = edge_index + N_EDGES;

    // ---- workspace budgets ----
    const size_t PAIRS_B    = (size_t)NP * PCAP * 8;        // 7,864,320
    const size_t PARTIALS_B = (size_t)NP * GOWN * PROW * 4; // 6,422,528
    const size_t need_binned = 3072 + PAIRS_B + PARTIALS_B + N_EDGES + N_NODES; // ~14.7 MB
    const size_t need_scoped = 2048 + (size_t)NXCD * N_NODES * 4 + N_EDGES + N_NODES; // ~4.3 MB

    char* ws = (char*)d_ws;

    if (ws_size >= need_binned) {
        // ---- binned (atomic-free accumulation) path ----
        float*    tabs     = (float*)ws;                         // 1 KiB
        float*    lossp    = (float*)(ws + 1024);                // 1 KiB (16 cells x 64B)
        uint32_t* cnt      = (uint32_t*)(ws + 2048);             // 1 KiB pad
        u64*      pairs    = (u64*)(ws + 3072);                  // 7.86 MB
        float*    partials = (float*)(ws + 3072 + PAIRS_B);      // 6.42 MB
        uint8_t*  ei       = (uint8_t*)(ws + 3072 + PAIRS_B + PARTIALS_B);
        uint8_t*  nib      = ei + N_EDGES;

        fused_pre<<<TAB_BLOCKS + NODE_BLOCKS + EI_BLOCKS, 256, 0, stream>>>(
            node_states, edge_states, node_emb, edge_emb,
            combine_W, combine_b, keep_W, keep_b, push_W, push_b,
            pushn_W, pushn_b, inc_W, inc_b, training_step,
            nullptr, cnt, ei, nib, tabs, lossp, out + N_EDGES, 0);

        const int ethreads8 = N_NONLOOP / EPT;   // 112500
        edge_compact<<<(ethreads8 + 255) / 256, 256, 0, stream>>>(
            scalars, srcp, dstp, brev, ei, nib, tabs, batch_scalars,
            cnt, pairs, lossp, out);

        bin_accum<<<NP * GOWN, 256, 0, stream>>>(pairs, cnt, partials);

        finalize_binned<<<(N_NODES + 255) / 256, 256, 0, stream>>>(
            scalars, brev, ei, nib, tabs, batch_scalars, partials, lossp,
            out, out + N_EDGES);
    } else {
        const bool scoped = (ws_size >= need_scoped);
        const int nc = scoped ? NXCD : 1;

        float*    tabs  = (float*)ws;
        float*    lossp = (float*)(ws + 1024);
        uint32_t* acc   = (uint32_t*)(ws + 2048);
        uint8_t*  ei    = (uint8_t*)(ws + 2048 + (size_t)nc * N_NODES * 4);
        uint8_t*  nib   = ei + N_EDGES;

        fused_pre<<<TAB_BLOCKS + NODE_BLOCKS + EI_BLOCKS, 256, 0, stream>>>(
            node_states, edge_states, node_emb, edge_emb,
            combine_W, combine_b, keep_W, keep_b, push_W, push_b,
            pushn_W, pushn_b, inc_W, inc_b, training_step,
            acc, nullptr, ei, nib, tabs, lossp, out + N_EDGES, nc);

        const int ethreads = N_NONLOOP / 4;   // 225000
        const int eblocks  = (ethreads + 255) / 256;
        if (scoped) {
            edge_kernel<1><<<eblocks, 256, 0, stream>>>(
                scalars, srcp, dstp, brev, ei, nib, tabs, batch_scalars,
                acc, lossp, out, out + N_EDGES);
            finalize_nodes<NXCD><<<(N_NODES + 255) / 256, 256, 0, stream>>>(
                scalars, brev, ei, nib, tabs, batch_scalars, acc, lossp,
                out, out + N_EDGES);
        } else {
            edge_kernel<0><<<eblocks, 256, 0, stream>>>(
                scalars, srcp, dstp, brev, ei, nib, tabs, batch_scalars,
                acc, lossp, out, out + N_EDGES);
            finalize_nodes<1><<<(N_NODES + 255) / 256, 256, 0, stream>>>(
                scalars, brev, ei, nib, tabs, batch_scalars, acc, lossp,
                out, out + N_EDGES);
        }
    }
}